// Round 2
// baseline (122.933 us; speedup 1.0000x reference)
//
#include <hip/hip_runtime.h>
#include <hip/hip_fp16.h>

// Trilinear 3D-LUT interpolation (image-adaptive-3DLUT forward).
// lut: [3, 33, 33, 33] fp32, x: [4, 3, 1024, 1024] fp32 in [0,1], out same as x.
//
// R2: LDS was the bottleneck (SQ_LDS_BANK_CONFLICT ~13us/CU + ~13us base on
// 4x ds_read2_b32 per pixel). Store the per-channel LUT as an fp16 PAIR array
// P[i] = half2(v[i], v[i+1]) -- each r-neighbor pair becomes ONE aligned
// ds_read_b32 (4 per pixel-channel), halving LDS address-lookups and cycles.
// Same 143.7 KB footprint (1 block/CU, 16 waves). Interp math stays fp32;
// fp16 corner quantization adds <=~2.4e-4 abs err (threshold 7.66e-3).

#define LUT_D   33
#define LUT_DD  (LUT_D * LUT_D)           // 1089
#define LUT_N   (LUT_D * LUT_D * LUT_D)   // 35937
#define HW4     (1024 * 1024 / 4)         // 262144 float4 groups per plane
#define NGROUPS (4 * HW4)                 // 1048576 groups per channel-pass
#define NCHUNKS 256
#define THREADS 1024
#define ITERS   (NGROUPS / NCHUNKS / THREADS)  // 4
#define STAGE4  (35936 / 4)               // 8984 float4 groups cover v[0..35935]

__device__ __forceinline__ unsigned int pack2(float a, float b) {
    __half2 h = __floats2half2_rn(a, b);
    return *(unsigned int*)&h;
}

__device__ __forceinline__ float2 unpack2(unsigned int p) {
    __half2 h = *(__half2*)&p;
    return __half22float2(h);
}

__global__ __launch_bounds__(THREADS)
void lut3d_trilerp_kernel(const float* __restrict__ lut,
                          const float* __restrict__ x,
                          float* __restrict__ out) {
    extern __shared__ __align__(16) unsigned int P[];  // P[i] = (v[i], v[i+1]) fp16x2

    const int bx    = blockIdx.x;
    const int c     = bx % 3;        // output channel
    const int chunk = bx / 3;        // pixel chunk

    const float* lc = lut + c * LUT_N;

    // ---- Stage: build fp16 pair array in LDS ----
    // Main body: 8984 float4 loads cover v[0..35935]; each group also needs
    // v[i+4] (<= 35936, in range) for its last pair. Element 35936's pair
    // partner (v[35937]) is never dereferenced (max pair index used is 34906).
    for (int i4 = threadIdx.x; i4 < STAGE4; i4 += THREADS) {
        const int i = i4 * 4;
        const float4 v  = *(const float4*)(lc + i);
        const float  v4 = lc[i + 4];
        uint4 w;
        w.x = pack2(v.x, v.y);
        w.y = pack2(v.y, v.z);
        w.z = pack2(v.z, v.w);
        w.w = pack2(v.w, v4);
        *(uint4*)(P + i) = w;   // byte offset 4*i, i%4==0 -> 16B aligned
    }
    if (threadIdx.x == 0) {
        P[LUT_N - 1] = pack2(lc[LUT_N - 1], 0.0f);
    }
    __syncthreads();

    const float4* x4 = (const float4*)x;
    float4*       o4 = (float4*)out;

    const int g0 = chunk * (NGROUPS / NCHUNKS) + (int)threadIdx.x;

#pragma unroll
    for (int it = 0; it < ITERS; ++it) {
        const int g     = g0 + it * THREADS;
        const int b_img = g >> 18;           // g / HW4  (HW4 = 2^18)
        const int hw4   = g & (HW4 - 1);
        const int ibase = b_img * 3 * HW4 + hw4;

        const float4 r4 = x4[ibase];
        const float4 g4 = x4[ibase + HW4];
        const float4 b4 = x4[ibase + 2 * HW4];

        const float rr[4] = {r4.x, r4.y, r4.z, r4.w};
        const float gg[4] = {g4.x, g4.y, g4.z, g4.w};
        const float bb[4] = {b4.x, b4.y, b4.z, b4.w};
        float oo[4];

#pragma unroll
        for (int k = 0; k < 4; ++k) {
            const float sr = rr[k] * 32.0f;
            const float sg = gg[k] * 32.0f;
            const float sb = bb[k] * 32.0f;
            // idx = clip(floor(s), 0, 31); d = s - idx   (matches reference)
            float fr = fminf(fmaxf(floorf(sr), 0.0f), 31.0f);
            float fg = fminf(fmaxf(floorf(sg), 0.0f), 31.0f);
            float fb = fminf(fmaxf(floorf(sb), 0.0f), 31.0f);
            const float dr = sr - fr;
            const float dg = sg - fg;
            const float db = sb - fb;
            const int ir = (int)fr, ig = (int)fg, ib = (int)fb;
            const int idx = (ib * LUT_D + ig) * LUT_D + ir;

            // 4 gathers, one aligned b32 each: (v[i], v[i+1]) fp16 pairs.
            const float2 a00 = unpack2(P[idx]);
            const float2 a01 = unpack2(P[idx + LUT_D]);
            const float2 a10 = unpack2(P[idx + LUT_DD]);
            const float2 a11 = unpack2(P[idx + LUT_DD + LUT_D]);

            const float l00 = a00.x + dr * (a00.y - a00.x);
            const float l01 = a01.x + dr * (a01.y - a01.x);
            const float l10 = a10.x + dr * (a10.y - a10.x);
            const float l11 = a11.x + dr * (a11.y - a11.x);
            const float l0  = l00 + dg * (l01 - l00);
            const float l1  = l10 + dg * (l11 - l10);
            oo[k] = l0 + db * (l1 - l0);
        }

        o4[(b_img * 3 + c) * HW4 + hw4] = make_float4(oo[0], oo[1], oo[2], oo[3]);
    }
}

extern "C" void kernel_launch(void* const* d_in, const int* in_sizes, int n_in,
                              void* d_out, int out_size, void* d_ws, size_t ws_size,
                              hipStream_t stream) {
    const float* lut = (const float*)d_in[0];  // [3, 33, 33, 33]
    const float* x   = (const float*)d_in[1];  // [4, 3, 1024, 1024]
    float*       out = (float*)d_out;

    const int grid = 3 * NCHUNKS;  // 768 blocks: c = bx%3, chunk = bx/3
    const size_t lds_bytes = LUT_N * sizeof(unsigned int);  // 143748 B

    lut3d_trilerp_kernel<<<grid, THREADS, lds_bytes, stream>>>(lut, x, out);
}

// Round 3
// 117.968 us; speedup vs baseline: 1.0421x; 1.0421x over previous
//
#include <hip/hip_runtime.h>
#include <hip/hip_fp16.h>

// Trilinear 3D-LUT interpolation (image-adaptive-3DLUT forward).
// lut: [3, 33, 33, 33] fp32, x: [4, 3, 1024, 1024] fp32 in [0,1], out same as x.
//
// R3: R2 showed the kernel is LATENCY-bound (all pipes <40%, VGPR=24 -> no MLP,
// 1 block/CU from 143.7 KB LDS). Changes:
//  - pre-pack kernel builds fp16-pair u32 LUT in d_ws; main kernel stages it
//    with async global_load_lds dwordx4 (no pack VALU, no VGPR roundtrip)
//  - hoist all 12 global x-loads before compute; batch all 16 LDS gathers per
//    iteration before unpack/math (source-level MLP/ILP)
//  - XCD swizzle: the 3 channel-blocks of a chunk map to the same XCD (share
//    the same 192 KB of x in that XCD's L2)
//  - nontemporal float4 stores (out never re-read)

#define LUT_D     33
#define LUT_DD    (LUT_D * LUT_D)            // 1089
#define LUT_N     (LUT_D * LUT_D * LUT_D)    // 35937
#define CH_STRIDE 35940                      // u32 per channel in ws, 16B-aligned
#define STAGE_G   (CH_STRIDE / 4)            // 8985 dwordx4 groups per channel
#define HW4       (1024 * 1024 / 4)          // 262144 float4 groups per plane
#define NGROUPS   (4 * HW4)                  // 1048576 groups per channel-pass
#define NCHUNKS   256
#define THREADS   1024
#define ITERS     (NGROUPS / NCHUNKS / THREADS)  // 4

typedef float vfloat4 __attribute__((ext_vector_type(4)));

__device__ __forceinline__ unsigned int pack2(float a, float b) {
    union { __half2 h; unsigned int u; } cv;
    cv.h = __floats2half2_rn(a, b);
    return cv.u;
}
__device__ __forceinline__ float2 unpack2(unsigned int p) {
    union { unsigned int u; __half2 h; } cv;
    cv.u = p;
    return __half22float2(cv.h);
}

// ---- Pass 1: pack lut fp32 -> fp16 pair array W[c*CH_STRIDE + i] = (v[i], v[i+1])
__global__ __launch_bounds__(256)
void lut_pack_kernel(const float* __restrict__ lut, unsigned int* __restrict__ W) {
    const int t = blockIdx.x * 256 + (int)threadIdx.x;
    if (t >= 3 * LUT_N) return;
    const int c = t / LUT_N;
    const int i = t - c * LUT_N;
    const float a = lut[t];
    const float b = (i + 1 < LUT_N) ? lut[t + 1] : 0.0f;
    W[c * CH_STRIDE + i] = pack2(a, b);
}

// ---- Pass 2: main interpolation
__global__ __launch_bounds__(THREADS)
void lut3d_trilerp_kernel(const unsigned int* __restrict__ W,
                          const float* __restrict__ x,
                          float* __restrict__ out) {
    extern __shared__ __align__(16) unsigned int P[];  // STAGE_G*16 = 143760 B

    const int bx   = blockIdx.x;
    // XCD-swizzle: blocks {g*24 + 8c + xcd} for c=0..2 share chunk g*8+xcd and
    // land on the same XCD (bx % 8 equal) -> x chunk shared in that L2.
    const int xcd  = bx & 7;
    const int c    = (bx >> 3) % 3;
    const int chunk = (bx / 24) * 8 + xcd;   // [0, 256)

    // Async stage: 143,760 B of packed pairs via global_load_lds dwordx4.
    const unsigned int* src = W + c * CH_STRIDE;  // byte offset %16 == 0
    for (int s = 0; s < 9; ++s) {
        const int gid = s * THREADS + (int)threadIdx.x;
        if (gid < STAGE_G) {
            __builtin_amdgcn_global_load_lds(
                (const __attribute__((address_space(1))) void*)(src + gid * 4),
                (__attribute__((address_space(3))) void*)(P + gid * 4),
                16, 0, 0);
        }
    }
    __syncthreads();  // emits s_waitcnt vmcnt(0) before s_barrier -> loads drained

    const float4* x4 = (const float4*)x;
    float4*       o4 = (float4*)out;

    const int g0 = chunk * (NGROUPS / NCHUNKS) + (int)threadIdx.x;

    // Phase A: hoist ALL global loads (12 float4 in flight).
    float4 R[ITERS], G[ITERS], B[ITERS];
    int obase[ITERS];
#pragma unroll
    for (int it = 0; it < ITERS; ++it) {
        const int g     = g0 + it * THREADS;
        const int b_img = g >> 18;            // g / HW4  (HW4 = 2^18)
        const int hw4   = g & (HW4 - 1);
        const int ibase = b_img * 3 * HW4 + hw4;
        R[it] = x4[ibase];
        G[it] = x4[ibase + HW4];
        B[it] = x4[ibase + 2 * HW4];
        obase[it] = ibase + c * HW4;          // (b_img*3 + c)*HW4 + hw4
    }

    // Phase B: per iteration, compute indices, batch-issue 16 gathers, then math.
#pragma unroll
    for (int it = 0; it < ITERS; ++it) {
        const float rr[4] = {R[it].x, R[it].y, R[it].z, R[it].w};
        const float gg[4] = {G[it].x, G[it].y, G[it].z, G[it].w};
        const float bb[4] = {B[it].x, B[it].y, B[it].z, B[it].w};

        int   idx[4];
        float dr[4], dg[4], db[4];
#pragma unroll
        for (int k = 0; k < 4; ++k) {
            const float sr = rr[k] * 32.0f;
            const float sg = gg[k] * 32.0f;
            const float sb = bb[k] * 32.0f;
            const float fr = fminf(fmaxf(floorf(sr), 0.0f), 31.0f);
            const float fg = fminf(fmaxf(floorf(sg), 0.0f), 31.0f);
            const float fb = fminf(fmaxf(floorf(sb), 0.0f), 31.0f);
            dr[k] = sr - fr;
            dg[k] = sg - fg;
            db[k] = sb - fb;
            idx[k] = ((int)fb * LUT_D + (int)fg) * LUT_D + (int)fr;
        }

        unsigned int q00[4], q01[4], q10[4], q11[4];
#pragma unroll
        for (int k = 0; k < 4; ++k) {
            q00[k] = P[idx[k]];
            q01[k] = P[idx[k] + LUT_D];
            q10[k] = P[idx[k] + LUT_DD];
            q11[k] = P[idx[k] + LUT_DD + LUT_D];
        }

        float oo[4];
#pragma unroll
        for (int k = 0; k < 4; ++k) {
            const float2 a00 = unpack2(q00[k]);
            const float2 a01 = unpack2(q01[k]);
            const float2 a10 = unpack2(q10[k]);
            const float2 a11 = unpack2(q11[k]);
            const float l00 = a00.x + dr[k] * (a00.y - a00.x);
            const float l01 = a01.x + dr[k] * (a01.y - a01.x);
            const float l10 = a10.x + dr[k] * (a10.y - a10.x);
            const float l11 = a11.x + dr[k] * (a11.y - a11.x);
            const float l0  = l00 + dg[k] * (l01 - l00);
            const float l1  = l10 + dg[k] * (l11 - l10);
            oo[k] = l0 + db[k] * (l1 - l0);
        }

        vfloat4 v = {oo[0], oo[1], oo[2], oo[3]};
        __builtin_nontemporal_store(v, (vfloat4*)&o4[obase[it]]);
    }
}

extern "C" void kernel_launch(void* const* d_in, const int* in_sizes, int n_in,
                              void* d_out, int out_size, void* d_ws, size_t ws_size,
                              hipStream_t stream) {
    const float*  lut = (const float*)d_in[0];   // [3, 33, 33, 33]
    const float*  x   = (const float*)d_in[1];   // [4, 3, 1024, 1024]
    float*        out = (float*)d_out;
    unsigned int* W   = (unsigned int*)d_ws;     // 3*CH_STRIDE u32 = 431,280 B

    const int pack_grid = (3 * LUT_N + 255) / 256;  // 422
    lut_pack_kernel<<<pack_grid, 256, 0, stream>>>(lut, W);

    const int grid = 3 * NCHUNKS;                    // 768
    const size_t lds_bytes = (size_t)STAGE_G * 16;   // 143,760 B
    lut3d_trilerp_kernel<<<grid, THREADS, lds_bytes, stream>>>(W, x, out);
}